// Round 3
// baseline (645.955 us; speedup 1.0000x reference)
//
#include <hip/hip_runtime.h>

typedef __attribute__((ext_vector_type(8))) short bf16x8;   // 8 bf16 = 4 VGPRs
typedef __attribute__((ext_vector_type(4))) float f32x4;    // MFMA C/D

__device__ __forceinline__ float bf2f(unsigned short u){
    unsigned int v = ((unsigned int)u) << 16;
    return __builtin_bit_cast(float, v);
}
__device__ __forceinline__ unsigned short f2bf(float f){
    unsigned int u = __builtin_bit_cast(unsigned int, f);
    u += 0x7FFFu + ((u >> 16) & 1u);   // RTNE
    return (unsigned short)(u >> 16);
}
// pack two floats -> (bf16(a) | bf16(b)<<16), round-half-up: 3 VALU ops total
__device__ __forceinline__ unsigned int pack2(float a, float b){
    unsigned int ua = __builtin_bit_cast(unsigned int, a) + 0x8000u;
    unsigned int ub = __builtin_bit_cast(unsigned int, b) + 0x8000u;
    return __builtin_amdgcn_perm(ub, ua, 0x07060302u);  // bytes: [ua.b2,ua.b3,ub.b2,ub.b3]
}

// ---- prep: W (K x 256) fp32 -> Wt (256 x K) bf16, LDS-tiled transpose ----
__global__ void prep_wt(const float* __restrict__ W, unsigned short* __restrict__ Wt, int K){
    __shared__ unsigned short L[256 * 72];          // 36864 B, row j stride 144B (16B-aligned)
    const int t = threadIdx.x;                      // t = j
    const int k0 = blockIdx.x << 6;
    #pragma unroll 4
    for (int kk = 0; kk < 64; kk++)
        L[t * 72 + kk] = f2bf(W[(size_t)(k0 + kk) * 256 + t]);   // coalesced read
    __syncthreads();
    const uint4* src = (const uint4*)(L + t * 72);
    uint4* dst = (uint4*)(Wt + (size_t)t * K + k0);
    #pragma unroll
    for (int q = 0; q < 8; q++) dst[q] = src[q];    // 16B-chunk writes
}

// ---- prep: x (b,m,d) fp32 -> Xt[b][d][m] bf16, LDS transpose, coalesced both sides ----
__global__ void prep_x(const float* __restrict__ x, unsigned short* __restrict__ Xt){
    __shared__ unsigned short L[64 * 40];           // [d][m pad 40]
    const int b = blockIdx.x;
    const int t = threadIdx.x;
    #pragma unroll
    for (int it = 0; it < 8; it++){
        int idx = it * 256 + t;                     // coalesced read
        int m = idx >> 6, d = idx & 63;
        L[d * 40 + m] = f2bf(x[(size_t)b * 2048 + idx]);
    }
    __syncthreads();
    uint4 v = *(const uint4*)(L + (t >> 2) * 40 + (t & 3) * 8);
    *(uint4*)(Xt + (size_t)b * 2048 + t * 8) = v;   // coalesced write
}

__global__ void init_out(float* __restrict__ out, const float* __restrict__ fcb){
    int i = blockIdx.x * 256 + threadIdx.x;
    if (i < 1024) out[i] = fcb[0];
}

// ---- fused CIN stage ----
// Block = 64 c (ONE batch elem), 4 waves; wave w: j in [64w, 64w+64), all 64 c.
// LDS exactly 32 KB -> 4 blocks/CU at __launch_bounds__(256,4).
template<int NN, int LOG2NN, int KTOT, int JX, bool HAS_HOUT>
__global__ __launch_bounds__(256, 4) void cin_stage(
    const unsigned short* __restrict__ Xt,
    const unsigned short* __restrict__ Hin,
    const unsigned short* __restrict__ Wt,
    const float* __restrict__ bias,
    const float* __restrict__ fcW,
    unsigned short* __restrict__ Hout,   // [b][d][n], n in [0,128)
    float* __restrict__ out)
{
    constexpr int KT = KTOT / 32;
    constexpr int ZS = 40;                           // Z/X row stride (shorts), 80 B
    constexpr int HS = (NN == 32) ? 40 : 136;        // Hl row stride (272 B, 16B-aligned)

    __shared__ unsigned short smem[16384];           // 32768 B exactly
    unsigned short* const Zb0 = smem;                // [64][40]  5120 B
    unsigned short* const Zb1 = smem + 2560;         // [64][40]  5120 B
    unsigned short* const Xl  = smem + 5120;         // [64][40]  5120 B
    unsigned short* const Hl  = (NN == 32) ? Xl : (smem + 7680);  // [64][136] 17408 B
    unsigned short* const Yl  = smem + 7680;         // epilogue overlay [c:64][n pad 136]

    const int t    = threadIdx.x;
    const int lane = t & 63;
    const int w    = t >> 6;
    const int li   = lane & 15;
    const int lq   = lane >> 4;
    const int b    = blockIdx.x;

    // ---- one-time staging: x (and h) into LDS, coalesced ----
    {
        const int c = t >> 2, v = t & 3;
        uint4 xv = *(const uint4*)(Xt + ((size_t)b << 11) + c * 32 + v * 8);
        *(uint4*)(Xl + c * ZS + v * 8) = xv;
        if (NN == 128){
            const uint4* hsrc = (const uint4*)(Hin + (size_t)((b << 6) + c) * 128 + v * 32);
            #pragma unroll
            for (int q = 0; q < 4; q++){
                uint4 hv = hsrc[q];
                *(uint4*)(Hl + c * HS + v * 32 + q * 8) = hv;
            }
        }
    }

    // Z-build: thread fills Zb[zc][zq*8 .. +8) = x[zc][m] * h[zc][n0..n0+8)
    const int zc = t & 63;
    const int zq = t >> 6;
    auto build = [&](unsigned short* zbuf, int kt){
        const int kg = (kt << 5) + (zq << 3);
        const int m  = kg >> LOG2NN;
        const int n0 = kg & (NN - 1);
        float xf = bf2f(Xl[zc * ZS + m]);
        uint4 h = *(const uint4*)(Hl + zc * HS + n0);
        const unsigned short* hu = (const unsigned short*)&h;
        uint4 zv;
        unsigned int* zp = (unsigned int*)&zv;
        #pragma unroll
        for (int q = 0; q < 4; q++)
            zp[q] = pack2(xf * bf2f(hu[2 * q]), xf * bf2f(hu[2 * q + 1]));
        *(uint4*)(zbuf + zc * ZS + (zq << 3)) = zv;
    };

    // A-fragments: lane reads Wt[j = w*64 + jt*16 + li][kt*32 + lq*8 .. +8)
    const unsigned short* wbase = Wt + (size_t)((w << 6) + li) * KTOT + (lq << 3);
    auto loadA = [&](int kt, bf16x8* A){
        const unsigned short* wk = wbase + (kt << 5);
        #pragma unroll
        for (int jt = 0; jt < 4; jt++)
            A[jt] = *(const bf16x8*)(wk + (size_t)jt * 16 * KTOT);
    };

    f32x4 acc[4][4];
    #pragma unroll
    for (int jt = 0; jt < 4; jt++)
        #pragma unroll
        for (int ct = 0; ct < 4; ct++)
            acc[jt][ct] = (f32x4){0.f, 0.f, 0.f, 0.f};

    auto mfma_step = [&](const unsigned short* Zr, const bf16x8* A){
        #pragma unroll
        for (int ct = 0; ct < 4; ct++){
            bf16x8 B = *(const bf16x8*)(Zr + ((ct << 4) + li) * ZS + (lq << 3));
            #pragma unroll
            for (int jt = 0; jt < 4; jt++)
                acc[jt][ct] = __builtin_amdgcn_mfma_f32_16x16x32_bf16(A[jt], B, acc[jt][ct], 0, 0, 0);
        }
    };

    bf16x8 A0[4], A1[4];
    loadA(0, A0);
    __syncthreads();            // staging visible
    build(Zb0, 0);
    __syncthreads();

    // 2x-unrolled K loop: ONE barrier per kt, no A-copy
    for (int kt = 0; kt < KT; kt += 2){
        loadA(kt + 1, A1);
        mfma_step(Zb0, A0);
        build(Zb1, kt + 1);
        __syncthreads();
        if (kt + 2 < KT) loadA(kt + 2, A0);
        mfma_step(Zb1, A1);
        if (kt + 2 < KT) build(Zb0, kt + 2);
        __syncthreads();
    }

    // ---- epilogue: bias+relu, fc partial, h-half -> Yl (transposed, b64 writes) ----
    float pfc = 0.f;
    #pragma unroll
    for (int jt = 0; jt < 4; jt++){
        const int jb = (w << 6) + (jt << 4) + (lq << 2);
        float bv[4], fv[4];
        #pragma unroll
        for (int r = 0; r < 4; r++){
            int j = jb + r;
            bv[r] = bias[j];
            fv[r] = (j < JX) ? fcW[j] : 0.f;
        }
        #pragma unroll
        for (int ct = 0; ct < 4; ct++){
            f32x4 f = acc[jt][ct];
            const int c = (ct << 4) + li;
            float y0 = f[0] + bv[0]; y0 = y0 > 0.f ? y0 : 0.f;
            float y1 = f[1] + bv[1]; y1 = y1 > 0.f ? y1 : 0.f;
            float y2 = f[2] + bv[2]; y2 = y2 > 0.f ? y2 : 0.f;
            float y3 = f[3] + bv[3]; y3 = y3 > 0.f ? y3 : 0.f;
            pfc += fv[0] * y0 + fv[1] * y1 + fv[2] * y2 + fv[3] * y3;
            if (HAS_HOUT && w >= 2){                 // j >= 128: h-half
                uint2 pk;
                pk.x = pack2(y0, y1);
                pk.y = pack2(y2, y3);
                *(uint2*)(Yl + c * 136 + (jb - 128)) = pk;
            }
        }
    }
    #pragma unroll
    for (int off = 32; off; off >>= 1) pfc += __shfl_xor(pfc, off, 64);
    if (lane == 0) atomicAdd(out + b, pfc);

    if (HAS_HOUT){
        __syncthreads();
        // Hout[(b*64 + c)*128 + n] = Yl[c][n], coalesced 64B/thread
        const int c2 = t >> 2, v2 = t & 3;
        unsigned short* gdst = Hout + (size_t)((b << 6) + c2) * 128 + v2 * 32;
        #pragma unroll
        for (int q = 0; q < 4; q++){
            uint4 tv = *(const uint4*)(Yl + c2 * 136 + v2 * 32 + q * 8);
            *(uint4*)(gdst + q * 8) = tv;
        }
    }
}

extern "C" void kernel_launch(void* const* d_in, const int* in_sizes, int n_in,
                              void* d_out, int out_size, void* d_ws, size_t ws_size,
                              hipStream_t stream){
    const float* x   = (const float*)d_in[0];
    const float* W0  = (const float*)d_in[1];
    const float* b0  = (const float*)d_in[2];
    const float* W1  = (const float*)d_in[3];
    const float* b1  = (const float*)d_in[4];
    const float* W2  = (const float*)d_in[5];
    const float* b2  = (const float*)d_in[6];
    const float* fcW = (const float*)d_in[7];
    const float* fcb = (const float*)d_in[8];
    float* out = (float*)d_out;

    char* ws = (char*)d_ws;
    unsigned short* Xt  = (unsigned short*)(ws);             // 4 MB
    unsigned short* Wt0 = (unsigned short*)(ws + 4194304);   // 512 KB
    unsigned short* Wt1 = (unsigned short*)(ws + 4718592);   // 2 MB
    unsigned short* Wt2 = (unsigned short*)(ws + 6815744);   // 2 MB
    unsigned short* H0  = (unsigned short*)(ws + 8912896);   // 16 MB
    unsigned short* H1  = (unsigned short*)(ws + 25690112);  // 16 MB (end 42467328)

    prep_wt<<<  16, 256, 0, stream>>>(W0, Wt0, 1024);
    prep_wt<<<  64, 256, 0, stream>>>(W1, Wt1, 4096);
    prep_wt<<<  64, 256, 0, stream>>>(W2, Wt2, 4096);
    prep_x <<<1024, 256, 0, stream>>>(x, Xt);
    init_out<<<4, 256, 0, stream>>>(out, fcb);

    cin_stage< 32, 5, 1024, 128, true ><<<1024, 256, 0, stream>>>(Xt, Xt, Wt0, b0, fcW,       H0, out);
    cin_stage<128, 7, 4096, 128, true ><<<1024, 256, 0, stream>>>(Xt, H0, Wt1, b1, fcW + 128, H1, out);
    cin_stage<128, 7, 4096, 256, false><<<1024, 256, 0, stream>>>(Xt, H1, Wt2, b2, fcW + 256, nullptr, out);
}

// Round 4
// 410.831 us; speedup vs baseline: 1.5723x; 1.5723x over previous
//
#include <hip/hip_runtime.h>

typedef __attribute__((ext_vector_type(8))) short bf16x8;   // 8 bf16 = 4 VGPRs
typedef __attribute__((ext_vector_type(4))) float f32x4;    // MFMA C/D

__device__ __forceinline__ float bf2f(unsigned short u){
    unsigned int v = ((unsigned int)u) << 16;
    return __builtin_bit_cast(float, v);
}
__device__ __forceinline__ unsigned short f2bf(float f){
    unsigned int u = __builtin_bit_cast(unsigned int, f);
    u += 0x7FFFu + ((u >> 16) & 1u);   // RTNE
    return (unsigned short)(u >> 16);
}
// pack two floats -> (bf16(a) | bf16(b)<<16), round-half-up: 3 VALU ops total
__device__ __forceinline__ unsigned int pack2(float a, float b){
    unsigned int ua = __builtin_bit_cast(unsigned int, a) + 0x8000u;
    unsigned int ub = __builtin_bit_cast(unsigned int, b) + 0x8000u;
    return __builtin_amdgcn_perm(ub, ua, 0x07060302u);  // bytes: [ua.b2,ua.b3,ub.b2,ub.b3]
}

// ---- prep: W (K x 256) fp32 -> Wt (256 x K) bf16, LDS-tiled transpose ----
__global__ void prep_wt(const float* __restrict__ W, unsigned short* __restrict__ Wt, int K){
    __shared__ unsigned short L[256 * 72];          // row j stride 144B (16B-aligned)
    const int t = threadIdx.x;                      // t = j
    const int k0 = blockIdx.x << 6;
    #pragma unroll 4
    for (int kk = 0; kk < 64; kk++)
        L[t * 72 + kk] = f2bf(W[(size_t)(k0 + kk) * 256 + t]);   // coalesced read
    __syncthreads();
    const uint4* src = (const uint4*)(L + t * 72);
    uint4* dst = (uint4*)(Wt + (size_t)t * K + k0);
    #pragma unroll
    for (int q = 0; q < 8; q++) dst[q] = src[q];
}

// ---- prep: x (b,m,d) fp32 -> Xt[b][d][m] bf16, LDS transpose ----
__global__ void prep_x(const float* __restrict__ x, unsigned short* __restrict__ Xt){
    __shared__ unsigned short L[64 * 40];           // [d][m pad 40]
    const int b = blockIdx.x;
    const int t = threadIdx.x;
    #pragma unroll
    for (int it = 0; it < 8; it++){
        int idx = it * 256 + t;                     // coalesced read
        int m = idx >> 6, d = idx & 63;
        L[d * 40 + m] = f2bf(x[(size_t)b * 2048 + idx]);
    }
    __syncthreads();
    uint4 v = *(const uint4*)(L + (t >> 2) * 40 + (t & 3) * 8);
    *(uint4*)(Xt + (size_t)b * 2048 + t * 8) = v;   // coalesced write
}

__global__ void init_out(float* __restrict__ out, const float* __restrict__ fcb){
    int i = blockIdx.x * 256 + threadIdx.x;
    if (i < 1024) out[i] = fcb[0];
}

// ---- fused CIN stage (R2 skeleton + pack2 + Xl2[m][c] + transposed epilogue) ----
// Block: 128 c (2 batch elems), 4 waves; wave w owns j in [64w, 64w+64).
// Z double-buffered, ONE barrier per kt; A prefetched one kt ahead from global.
template<int NN, int LOG2NN, int KTOT, int JX, bool HAS_HOUT>
__global__ __launch_bounds__(256, 2) void cin_stage(
    const unsigned short* __restrict__ Xt,
    const unsigned short* __restrict__ Hin,
    const unsigned short* __restrict__ Wt,
    const float* __restrict__ bias,
    const float* __restrict__ fcW,      // pre-offset for this layer
    unsigned short* __restrict__ Hout,  // [b][d][n] bf16, n in [0,128)
    float* __restrict__ out)
{
    constexpr int KT = KTOT / 32;
    constexpr int ZS = 40;                           // Z row stride (shorts)
    constexpr int XS = 136;                          // Xl2 row stride [m][c pad]
    constexpr int HS = (NN == 32) ? 40 : 136;        // Hl row stride [c][n pad]

    __shared__ unsigned short smem[32000];           // 64000 B -> 2 blocks/CU
    unsigned short* const Zb0 = smem;                // [128][40]  5120 sh
    unsigned short* const Zb1 = smem + 5120;         // [128][40]  5120 sh
    unsigned short* const Xl2 = smem + 10240;        // [32][136]  4352 sh
    unsigned short* const Hl  = smem + 14592;        // [128][HS]  <=17408 sh
    unsigned short* const Yl  = smem + 14592;        // epilogue overlay [c:128][n pad 136]

    const int t    = threadIdx.x;
    const int lane = t & 63;
    const int w    = t >> 6;
    const int li   = lane & 15;
    const int lq   = lane >> 4;
    const int bpair = blockIdx.x;

    // ---- one-time staging: x -> Xl2 (transposed), h -> Hl, coalesced global reads ----
    {
        const int c = t >> 1, half = t & 1;
        const int be = (bpair << 1) + (c >> 6), d = c & 63;
        const unsigned short* xsrc = Xt + ((size_t)be << 11) + (d << 5) + (half << 4);
        uint4 xa = ((const uint4*)xsrc)[0];
        uint4 xb = ((const uint4*)xsrc)[1];
        #pragma unroll
        for (int q = 0; q < 8; q++)
            Xl2[(half * 16 + q) * XS + c] = ((const unsigned short*)&xa)[q];
        #pragma unroll
        for (int q = 0; q < 8; q++)
            Xl2[(half * 16 + 8 + q) * XS + c] = ((const unsigned short*)&xb)[q];
        const int nh = half * (NN / 2);
        const uint4* hsrc = (const uint4*)(Hin + (size_t)((be << 6) + d) * NN + nh);
        #pragma unroll
        for (int q = 0; q < NN / 16; q++){
            uint4 hv = hsrc[q];
            *(uint4*)(Hl + c * HS + nh + q * 8) = hv;
        }
    }

    // Z-build: thread fills Zb[zc][zkh*16 .. +16)
    const int zc  = t & 127;
    const int zkh = t >> 7;
    auto build = [&](unsigned short* zbuf, int kt){
        const int kg = (kt << 5) + (zkh << 4);
        const int m  = kg >> LOG2NN;
        const int n0 = kg & (NN - 1);
        float xf = bf2f(Xl2[m * XS + zc]);           // conflict-free (consecutive c)
        const uint4* hsrc = (const uint4*)(Hl + zc * HS + n0);
        uint4 h0 = hsrc[0], h1 = hsrc[1];
        const unsigned short* hu0 = (const unsigned short*)&h0;
        const unsigned short* hu1 = (const unsigned short*)&h1;
        uint4 z0, z1;
        unsigned int* zp0 = (unsigned int*)&z0;
        unsigned int* zp1 = (unsigned int*)&z1;
        #pragma unroll
        for (int q = 0; q < 4; q++)
            zp0[q] = pack2(xf * bf2f(hu0[2 * q]), xf * bf2f(hu0[2 * q + 1]));
        #pragma unroll
        for (int q = 0; q < 4; q++)
            zp1[q] = pack2(xf * bf2f(hu1[2 * q]), xf * bf2f(hu1[2 * q + 1]));
        uint4* zdst = (uint4*)(zbuf + zc * ZS + (zkh << 4));
        zdst[0] = z0;
        zdst[1] = z1;
    };

    // A-fragments: lane reads Wt[j = w*64 + jt*16 + li][kt*32 + lq*8 .. +8)
    const unsigned short* wbase = Wt + (size_t)((w << 6) + li) * KTOT + (lq << 3);
    auto loadA = [&](int kt, bf16x8* A){
        const unsigned short* wk = wbase + (kt << 5);
        #pragma unroll
        for (int jt = 0; jt < 4; jt++)
            A[jt] = *(const bf16x8*)(wk + (size_t)jt * 16 * KTOT);
    };

    f32x4 acc[4][8];
    #pragma unroll
    for (int jt = 0; jt < 4; jt++)
        #pragma unroll
        for (int ct = 0; ct < 8; ct++)
            acc[jt][ct] = (f32x4){0.f, 0.f, 0.f, 0.f};

    auto mfma_step = [&](const unsigned short* Zr, const bf16x8* A){
        #pragma unroll
        for (int ct = 0; ct < 8; ct++){
            bf16x8 B = *(const bf16x8*)(Zr + ((ct << 4) + li) * ZS + (lq << 3));
            #pragma unroll
            for (int jt = 0; jt < 4; jt++)
                acc[jt][ct] = __builtin_amdgcn_mfma_f32_16x16x32_bf16(A[jt], B, acc[jt][ct], 0, 0, 0);
        }
    };

    bf16x8 A0[4], A1[4];
    loadA(0, A0);
    __syncthreads();            // staging visible
    build(Zb0, 0);
    __syncthreads();

    // 2x-unrolled K loop: ONE barrier per kt, no A-copy
    for (int kt = 0; kt < KT; kt += 2){
        loadA(kt + 1, A1);
        mfma_step(Zb0, A0);
        build(Zb1, kt + 1);
        __syncthreads();
        if (kt + 2 < KT) loadA(kt + 2, A0);
        mfma_step(Zb1, A1);
        if (kt + 2 < KT) build(Zb0, kt + 2);
        __syncthreads();
    }

    // ---- epilogue: bias+relu, fc partials, h-half -> Yl[c][n] (uint2 writes) ----
    float pfc0 = 0.f, pfc1 = 0.f;
    #pragma unroll
    for (int jt = 0; jt < 4; jt++){
        const int jb = (w << 6) + (jt << 4) + (lq << 2);
        float bv[4], fv[4];
        #pragma unroll
        for (int r = 0; r < 4; r++){
            int j = jb + r;
            bv[r] = bias[j];
            fv[r] = (j < JX) ? fcW[j] : 0.f;
        }
        #pragma unroll
        for (int ct = 0; ct < 8; ct++){
            f32x4 f = acc[jt][ct];
            const int c = (ct << 4) + li;
            float y0 = f[0] + bv[0]; y0 = y0 > 0.f ? y0 : 0.f;
            float y1 = f[1] + bv[1]; y1 = y1 > 0.f ? y1 : 0.f;
            float y2 = f[2] + bv[2]; y2 = y2 > 0.f ? y2 : 0.f;
            float y3 = f[3] + bv[3]; y3 = y3 > 0.f ? y3 : 0.f;
            float ps = fv[0] * y0 + fv[1] * y1 + fv[2] * y2 + fv[3] * y3;
            if (HAS_HOUT && w >= 2){                 // j >= 128: h-half
                uint2 pk;
                pk.x = pack2(y0, y1);
                pk.y = pack2(y2, y3);
                *(uint2*)(Yl + c * 136 + (jb - 128)) = pk;
            }
            if (ct < 4) pfc0 += ps; else pfc1 += ps;
        }
    }
    #pragma unroll
    for (int off = 32; off; off >>= 1){
        pfc0 += __shfl_xor(pfc0, off, 64);
        pfc1 += __shfl_xor(pfc1, off, 64);
    }
    if (lane == 0){
        atomicAdd(out + bpair * 2 + 0, pfc0);
        atomicAdd(out + bpair * 2 + 1, pfc1);
    }

    if (HAS_HOUT){
        __syncthreads();
        // Hout[(bpair*128 + c)*128 + n] = Yl[c][n], coalesced b128 both sides
        const int c2 = t >> 1, v2 = t & 1;
        unsigned short* gdst = Hout + (size_t)((bpair << 7) + c2) * 128 + v2 * 64;
        #pragma unroll
        for (int q = 0; q < 8; q++){
            uint4 tv = *(const uint4*)(Yl + c2 * 136 + v2 * 64 + q * 8);
            *(uint4*)(gdst + q * 8) = tv;
        }
    }
}

extern "C" void kernel_launch(void* const* d_in, const int* in_sizes, int n_in,
                              void* d_out, int out_size, void* d_ws, size_t ws_size,
                              hipStream_t stream){
    const float* x   = (const float*)d_in[0];
    const float* W0  = (const float*)d_in[1];
    const float* b0  = (const float*)d_in[2];
    const float* W1  = (const float*)d_in[3];
    const float* b1  = (const float*)d_in[4];
    const float* W2  = (const float*)d_in[5];
    const float* b2  = (const float*)d_in[6];
    const float* fcW = (const float*)d_in[7];
    const float* fcb = (const float*)d_in[8];
    float* out = (float*)d_out;

    char* ws = (char*)d_ws;
    unsigned short* Xt  = (unsigned short*)(ws);             // 4 MB
    unsigned short* Wt0 = (unsigned short*)(ws + 4194304);   // 512 KB
    unsigned short* Wt1 = (unsigned short*)(ws + 4718592);   // 2 MB
    unsigned short* Wt2 = (unsigned short*)(ws + 6815744);   // 2 MB
    unsigned short* H0  = (unsigned short*)(ws + 8912896);   // 16 MB
    unsigned short* H1  = (unsigned short*)(ws + 25690112);  // 16 MB (end 42467328)

    prep_wt<<<  16, 256, 0, stream>>>(W0, Wt0, 1024);
    prep_wt<<<  64, 256, 0, stream>>>(W1, Wt1, 4096);
    prep_wt<<<  64, 256, 0, stream>>>(W2, Wt2, 4096);
    prep_x <<<1024, 256, 0, stream>>>(x, Xt);
    init_out<<<4, 256, 0, stream>>>(out, fcb);

    cin_stage< 32, 5, 1024, 128, true ><<<512, 256, 0, stream>>>(Xt, Xt, Wt0, b0, fcW,       H0, out);
    cin_stage<128, 7, 4096, 128, true ><<<512, 256, 0, stream>>>(Xt, H0, Wt1, b1, fcW + 128, H1, out);
    cin_stage<128, 7, 4096, 256, false><<<512, 256, 0, stream>>>(Xt, H1, Wt2, b2, fcW + 256, nullptr, out);
}